// Round 5
// baseline (182.051 us; speedup 1.0000x reference)
//
#include <hip/hip_runtime.h>

typedef _Float16 f16x8 __attribute__((ext_vector_type(8)));
typedef float f32x4 __attribute__((ext_vector_type(4)));

// Monotone rel-completion counter: exactly 576 increments per graph replay,
// so (count % 576)==575 identifies the last block of THIS replay without reset.
__device__ unsigned g_rel_done = 0;

// XCD-affinity: blocks touching image n are swizzled so blockIdx ≡ n (mod 8)
// → producer/consumer share one XCD's L2 (kept from round 3, +11 us).
// Deep burst staging in convs kept from round 4.
// This round: rel_k __launch_bounds__(256,2) — round-4 profile showed
// VGPR_Count=72 for a loop needing ~150 live VGPRs (bf[4][4]=64 alone):
// the compiler was re-loading B-fragments from global inside the q-loop.
// Min-2-waves/EU caps VGPR at 256, letting bf/uf/acc stay resident.

// ---------------- conv1: (24,3,64,64) -> (24,32,32,32), stride2 SAME, relu
__global__ void __launch_bounds__(256) conv1_k(
        const float* __restrict__ sx, const float* __restrict__ qx,
        const float* __restrict__ w, const float* __restrict__ bias,
        float* __restrict__ out,
        const float* __restrict__ Wg2, _Float16* __restrict__ W2h) {
    if (blockIdx.x == 768) {
        for (int s = 0; s < 4; s++) {
            int slot = threadIdx.x + 256*s;      // 0..1023
            int tile = slot >> 6, lane = slot & 63;
            int kt = tile >> 2, nt = tile & 3;
            int quad = lane >> 4, col = lane & 15;
            f16x8 t;
            #pragma unroll
            for (int jj = 0; jj < 8; jj++)
                t[jj] = (_Float16)Wg2[(kt*32 + quad*8 + jj)*64 + nt*16 + col];
            *(f16x8*)&W2h[slot*8] = t;
        }
        return;
    }
    int r8 = blockIdx.x & 7, q = blockIdx.x >> 3;   // q 0..95
    int n  = (q >> 5)*8 + r8;    // 0..23
    int oc = q & 31;             // 0..31
    int bi = n / 6, si = n % 6;
    const float* inp = (si < 5) ? sx + (size_t)((bi*5+si)*3)*4096
                                : qx + (size_t)(bi*3)*4096;
    __shared__ __align__(16) float ish[3*4352];   // 3 planes, row stride 68
    __shared__ float wl[27];
    __shared__ float bl;
    const int tid = threadIdx.x;
    #pragma unroll
    for (int j = 0; j < 12; j++) {               // 3072 f32x4 burst
        int k = tid + j*256;
        f32x4 t = *(const f32x4*)&inp[k*4];
        int plane = k >> 10, rem = k & 1023, row = rem >> 4, c4 = (rem & 15)*4;
        *(f32x4*)&ish[plane*4352 + row*68 + c4] = t;
    }
    if (tid < 27) wl[tid] = w[oc*27 + tid];
    if (tid == 31) bl = bias[oc];
    __syncthreads();
    for (int idx = tid; idx < 1024; idx += 256) {
        int oy = idx >> 5, ox = idx & 31;
        float acc = bl;
        #pragma unroll
        for (int ic = 0; ic < 3; ic++) {
            const float* ip = &ish[ic*4352];
            #pragma unroll
            for (int dy = 0; dy < 3; dy++) {
                int iy = 2*oy + dy;
                if (iy >= 64) continue;
                #pragma unroll
                for (int dx = 0; dx < 3; dx++) {
                    int ix = 2*ox + dx;
                    if (ix >= 64) continue;
                    acc += ip[iy*68+ix] * wl[ic*9 + dy*3 + dx];
                }
            }
        }
        out[(size_t)(n*32+oc)*1024 + idx] = fmaxf(acc, 0.f);
    }
}

// ---------------- conv2: (24,32,32,32) -> (24,48,16,16), oc-group=4
__global__ void __launch_bounds__(256) conv2_k(
        const float* __restrict__ in, const float* __restrict__ w,
        const float* __restrict__ bias, float* __restrict__ out) {
    int r8 = blockIdx.x & 7, q = blockIdx.x >> 3;   // q 0..35
    int n   = (q / 12)*8 + r8;   // 0..23
    int ocg = q % 12;
    __shared__ __align__(16) float wl[1152];
    __shared__ __align__(16) float pin[16*1152];    // 16 planes, 32 rows x stride 36
    const int tid = threadIdx.x;
    const float* ib = in + (size_t)n*32*1024;
    // burst: half0 -> LDS
    #pragma unroll
    for (int j = 0; j < 16; j++) {
        int k = tid + j*256;                        // 0..4095
        f32x4 t = *(const f32x4*)&ib[k*4];
        int s = k >> 8, rem = k & 255, row = rem >> 3, c4 = (rem & 7)*4;
        *(f32x4*)&pin[s*1152 + row*36 + c4] = t;
    }
    // burst: half1 -> regs (stays in flight across half0's LDS writes)
    f32x4 rb[16];
    #pragma unroll
    for (int j = 0; j < 16; j++) {
        int k = tid + j*256;
        rb[j] = *(const f32x4*)&ib[16384 + k*4];
    }
    for (int e = tid; e < 288; e += 256)
        *(f32x4*)&wl[e*4] = *(const f32x4*)&w[ocg*1152 + e*4];
    __syncthreads();
    int oy = tid >> 4, ox = tid & 15;
    float a0 = bias[ocg*4+0], a1 = bias[ocg*4+1];
    float a2 = bias[ocg*4+2], a3 = bias[ocg*4+3];
    #pragma unroll 4
    for (int ic = 0; ic < 16; ic++) {
        const float* pp = &pin[ic*1152];
        float tap[9];
        #pragma unroll
        for (int dy = 0; dy < 3; dy++)
            #pragma unroll
            for (int dx = 0; dx < 3; dx++) {
                int iy = 2*oy+dy, ix = 2*ox+dx;
                tap[dy*3+dx] = (iy < 32 && ix < 32) ? pp[iy*36 + ix] : 0.f;
            }
        #pragma unroll
        for (int t = 0; t < 9; t++) {
            a0 += tap[t]*wl[0*288 + ic*9 + t];
            a1 += tap[t]*wl[1*288 + ic*9 + t];
            a2 += tap[t]*wl[2*288 + ic*9 + t];
            a3 += tap[t]*wl[3*288 + ic*9 + t];
        }
    }
    __syncthreads();
    #pragma unroll
    for (int j = 0; j < 16; j++) {
        int k = tid + j*256;
        int s = k >> 8, rem = k & 255, row = rem >> 3, c4 = (rem & 7)*4;
        *(f32x4*)&pin[s*1152 + row*36 + c4] = rb[j];
    }
    __syncthreads();
    #pragma unroll 4
    for (int ic = 16; ic < 32; ic++) {
        const float* pp = &pin[(ic-16)*1152];
        float tap[9];
        #pragma unroll
        for (int dy = 0; dy < 3; dy++)
            #pragma unroll
            for (int dx = 0; dx < 3; dx++) {
                int iy = 2*oy+dy, ix = 2*ox+dx;
                tap[dy*3+dx] = (iy < 32 && ix < 32) ? pp[iy*36 + ix] : 0.f;
            }
        #pragma unroll
        for (int t = 0; t < 9; t++) {
            a0 += tap[t]*wl[0*288 + ic*9 + t];
            a1 += tap[t]*wl[1*288 + ic*9 + t];
            a2 += tap[t]*wl[2*288 + ic*9 + t];
            a3 += tap[t]*wl[3*288 + ic*9 + t];
        }
    }
    size_t ob = (size_t)(n*48 + ocg*4)*256 + tid;
    out[ob        ] = fmaxf(a0, 0.f);
    out[ob + 256  ] = fmaxf(a1, 0.f);
    out[ob + 512  ] = fmaxf(a2, 0.f);
    out[ob + 768  ] = fmaxf(a3, 0.f);
}

// ---------------- conv3 + fused mean-pool: (24,48,16,16) -> (24,64,8,8) + mf(24,64)
__global__ void __launch_bounds__(256) conv3_k(
        const float* __restrict__ in, const float* __restrict__ w,
        const float* __restrict__ bias, float* __restrict__ out,
        float* __restrict__ mf) {
    int r8 = blockIdx.x & 7, q = blockIdx.x >> 3;   // q 0..23
    int n   = (q >> 3)*8 + r8;   // 0..23
    int ocg = q & 7;
    __shared__ __align__(16) float wl[3456];
    __shared__ __align__(16) float pin[48*320];     // 48 planes, 16 rows x stride 20
    const int tid = threadIdx.x;
    const float* ib = in + (size_t)n*48*256;
    #pragma unroll
    for (int j = 0; j < 12; j++) {                  // 3072 f32x4 burst
        int k = tid + j*256;
        f32x4 t = *(const f32x4*)&ib[k*4];
        int plane = k >> 6, rem = k & 63, row = rem >> 2, c4 = (rem & 3)*4;
        *(f32x4*)&pin[plane*320 + row*20 + c4] = t;
    }
    for (int e = tid; e < 864; e += 256)
        *(f32x4*)&wl[e*4] = *(const f32x4*)&w[ocg*3456 + e*4];
    __syncthreads();
    int pix = tid & 63, osub = tid >> 6;
    int oy = pix >> 3, ox = pix & 7;
    int ol0 = osub*2;
    float a0 = bias[ocg*8 + ol0], a1 = bias[ocg*8 + ol0 + 1];
    #pragma unroll 4
    for (int ic = 0; ic < 48; ic++) {
        const float* pp = &pin[ic*320];
        float tap[9];
        #pragma unroll
        for (int dy = 0; dy < 3; dy++)
            #pragma unroll
            for (int dx = 0; dx < 3; dx++) {
                int iy = 2*oy+dy, ix = 2*ox+dx;
                tap[dy*3+dx] = (iy < 16 && ix < 16) ? pp[iy*20 + ix] : 0.f;
            }
        #pragma unroll
        for (int t = 0; t < 9; t++) {
            a0 += tap[t]*wl[ ol0   *432 + ic*9 + t];
            a1 += tap[t]*wl[(ol0+1)*432 + ic*9 + t];
        }
    }
    float r0 = fmaxf(a0, 0.f), r1 = fmaxf(a1, 0.f);
    out[(size_t)(n*64 + ocg*8 + ol0  )*64 + pix] = r0;
    out[(size_t)(n*64 + ocg*8 + ol0+1)*64 + pix] = r1;
    #pragma unroll
    for (int off = 32; off >= 1; off >>= 1) {
        r0 += __shfl_xor(r0, off, 64);
        r1 += __shfl_xor(r1, off, 64);
    }
    if (pix == 0) {
        mf[n*64 + ocg*8 + ol0    ] = r0 * (1.f/64.f);
        mf[n*64 + ocg*8 + ol0 + 1] = r1 * (1.f/64.f);
    }
}

// ---------------- uv (blocks 0..383, f16 out, swizzled) + cls head (384..407)
__global__ void uvcls_k(const float* __restrict__ feat3, const float* __restrict__ Wg1,
                        const float* __restrict__ bg1, _Float16* __restrict__ u,
                        _Float16* __restrict__ v,
                        const float* __restrict__ mf, const int* __restrict__ sy,
                        const int* __restrict__ qy, const float* __restrict__ Wlog,
                        const float* __restrict__ blog, float* __restrict__ rv) {
    int tid = threadIdx.x;   // 128
    if (blockIdx.x >= 384) {
        int n = blockIdx.x - 384;
        if (tid >= 64) return;
        int lane = tid;
        float s = blog[lane];
        for (int c = 0; c < 64; c++) s += mf[n*64 + c] * Wlog[c*64 + lane];
        float mx = s;
        #pragma unroll
        for (int off = 32; off >= 1; off >>= 1) mx = fmaxf(mx, __shfl_xor(mx, off, 64));
        float p = __expf(s - mx);
        float se = p;
        #pragma unroll
        for (int off = 32; off >= 1; off >>= 1) se += __shfl_xor(se, off, 64);
        int bi = n/6, si = n%6;
        int lab = (si < 5) ? sy[bi*5+si] : qy[bi];
        float s_lab = __shfl(s, lab, 64);
        if (lane == 0) rv[n] = -(s_lab - mx - __logf(se));
        return;
    }
    int r8 = blockIdx.x & 7, q = blockIdx.x >> 3;  // q 0..47
    int bs = (q >> 4)*8 + r8;    // 0..23
    int pg = q & 15;             // p-group of 4
    __shared__ float a4[4][66];
    for (int e = tid; e < 264; e += 128) {
        int pl = e / 66, c = e % 66;
        int p = pg*4 + pl;
        float vv;
        if (c < 64)       vv = feat3[(size_t)(bs*64 + c)*64 + p];
        else if (c == 64) vv = (float)(p >> 3) * 0.125f;
        else              vv = (float)(p & 7) * 0.125f;
        a4[pl][c] = vv;
    }
    __syncthreads();
    float us[4] = {0.f,0.f,0.f,0.f};
    float bg = bg1[tid];
    float vs[4] = {bg,bg,bg,bg};
    for (int c = 0; c < 66; c++) {
        float wa = Wg1[c*128 + tid];
        float wb = Wg1[(66+c)*128 + tid];
        #pragma unroll
        for (int pl = 0; pl < 4; pl++) {
            us[pl] += a4[pl][c]*wa;
            vs[pl] += a4[pl][c]*wb;
        }
    }
    #pragma unroll
    for (int pl = 0; pl < 4; pl++) {
        int p = pg*4 + pl;
        u[(size_t)(bs*64+p)*128 + tid] = (_Float16)us[pl];
        v[(size_t)(bs*64+p)*128 + tid] = (_Float16)vs[pl];
    }
}

// ---------------- relation core + fused loss epilogue (last block)
// xfpT layout: [feature f (64)][gm = b*144 + (j*6+i)*4 + qc (576)]
// __launch_bounds__(256,2): VGPR cap 256 so bf[4][4](64)+uf(16)+acc(16)
// stay register-resident (round-4 VGPR=72 forced in-loop B reloads).
__global__ void __launch_bounds__(256, 2) rel_k(
        const _Float16* __restrict__ U, const _Float16* __restrict__ V,
        const _Float16* __restrict__ W2h, const float* __restrict__ bg2,
        float* __restrict__ xfpT,
        const float* __restrict__ rv,
        const int* __restrict__ sy, const int* __restrict__ qy,
        const float* __restrict__ Wf1, const float* __restrict__ bf1,
        const float* __restrict__ Wf2, const float* __restrict__ bf2,
        float* __restrict__ out) {
    __shared__ __align__(16) float smem[1792];     // union: rel {Vsh,xfred} / loss arrays
    __shared__ unsigned lastflag;
    _Float16* Vsh   = (_Float16*)smem;             // 2048 halves = 4 KB
    float*    xfred = smem + 1024;                 // [4][64]

    int r8 = blockIdx.x & 7, qq = blockIdx.x >> 3;   // batch b pinned to XCD pair
    int b = r8 >> 1;
    int m = (qq << 1) | (r8 & 1);    // 0..143
    int cb = m >> 2, qc = m & 3;
    int j = cb / 6, i = cb % 6;
    int tid  = threadIdx.x;
    int wv   = tid >> 6, lane = tid & 63;
    int col  = lane & 15, quad = lane >> 4;

    const _Float16* ub = U + (size_t)(b*6 + i)*8192;
    const _Float16* vb = V + (size_t)(b*6 + j)*8192 + qc*16*128;

    *(f16x8*)&Vsh[tid*8] = *(const f16x8*)&vb[tid*8];

    f16x8 uf[4];
    {
        const _Float16* up = ub + (wv*16 + col)*128 + quad*8;
        #pragma unroll
        for (int kt = 0; kt < 4; kt++) uf[kt] = *(const f16x8*)&up[kt*32];
    }
    f16x8 bf[4][4];
    #pragma unroll
    for (int kt = 0; kt < 4; kt++)
        #pragma unroll
        for (int nt = 0; nt < 4; nt++)
            bf[kt][nt] = *(const f16x8*)&W2h[(size_t)(((kt*4+nt)*64) + lane)*8];
    float bgv[4];
    #pragma unroll
    for (int nt = 0; nt < 4; nt++) bgv[nt] = bg2[nt*16 + col];

    __syncthreads();

    float sums[4] = {0.f,0.f,0.f,0.f};
    for (int qi = 0; qi < 16; qi++) {
        const _Float16* vp = &Vsh[qi*128 + quad*8];
        f32x4 acc[4];
        #pragma unroll
        for (int nt = 0; nt < 4; nt++)
            acc[nt] = (f32x4){bgv[nt], bgv[nt], bgv[nt], bgv[nt]};
        #pragma unroll
        for (int kt = 0; kt < 4; kt++) {
            f16x8 vf = *(const f16x8*)&vp[kt*32];
            f16x8 af = uf[kt] + vf;
            af = __builtin_elementwise_max(af, (f16x8){0,0,0,0,0,0,0,0});
            #pragma unroll
            for (int nt = 0; nt < 4; nt++)
                acc[nt] = __builtin_amdgcn_mfma_f32_16x16x32_f16(af, bf[kt][nt], acc[nt], 0, 0, 0);
        }
        #pragma unroll
        for (int nt = 0; nt < 4; nt++)
            #pragma unroll
            for (int rr = 0; rr < 4; rr++)
                sums[nt] += fmaxf(acc[nt][rr], 0.f);
    }

    #pragma unroll
    for (int nt = 0; nt < 4; nt++) {
        sums[nt] += __shfl_xor(sums[nt], 16, 64);
        sums[nt] += __shfl_xor(sums[nt], 32, 64);
    }
    if (lane < 16) {
        #pragma unroll
        for (int nt = 0; nt < 4; nt++) xfred[wv*64 + nt*16 + lane] = sums[nt];
    }
    __syncthreads();
    if (tid < 64)
        xfpT[(size_t)tid*576 + (unsigned)(b*144 + m)] =
            xfred[tid] + xfred[64+tid] + xfred[128+tid] + xfred[192+tid];

    // ---- last-block-done handoff (release on arrive, acquire on depart) ----
    __syncthreads();                                // drains this block's stores
    if (tid == 0) {
        __threadfence();                            // wb dirty L2 (agent scope)
        unsigned my = __hip_atomic_fetch_add(&g_rel_done, 1u, __ATOMIC_ACQ_REL,
                                             __HIP_MEMORY_SCOPE_AGENT);
        lastflag = ((my % 576u) == 575u) ? 1u : 0u;
    }
    __syncthreads();
    if (!lastflag) return;
    if (tid == 0)
        (void)__hip_atomic_load(&g_rel_done, __ATOMIC_ACQUIRE,
                                __HIP_MEMORY_SCOPE_AGENT);  // inv L1/L2 once
    __syncthreads();

    // ---- loss epilogue (same math as verified loss_k; coalesced xfpT reads) ----
    {
        float* Wf1sh = smem;                 // 1024
        float* wf2sh = smem + 1024;          // 16
        float* bf1sh = smem + 1040;          // 16
        float* Pm    = smem + 1056;          // 144
        int*   lab   = (int*)(smem + 1200);  // 24
        float* red   = smem + 1232;          // 256
        float* ratio = smem + 1488;          // 4
        for (int e = tid; e < 1024; e += 256) Wf1sh[e] = Wf1[e];
        if (tid < 16) { wf2sh[tid] = Wf2[tid]; bf1sh[tid] = bf1[tid]; }
        if (tid < 24) { int bi = tid/6, si = tid%6; lab[tid] = (si < 5) ? sy[bi*5+si] : qy[bi]; }
        __syncthreads();
        if (tid < 144) {
            float hid[16];
            #pragma unroll
            for (int h = 0; h < 16; h++) hid[h] = bf1sh[h];
            for (int nn = 0; nn < 64; nn++) {
                f32x4 vv = *(const f32x4*)&xfpT[(size_t)nn*576 + tid*4];
                float x = vv[0] + vv[1] + vv[2] + vv[3];   // qc ascending — same order
                #pragma unroll
                for (int h = 0; h < 16; h++) hid[h] += x * Wf1sh[nn*16 + h];
            }
            float sc = bf2[0];
            #pragma unroll
            for (int h = 0; h < 16; h++) sc += fmaxf(hid[h], 0.f) * wf2sh[h];
            Pm[tid] = 1.f/(1.f + __expf(-sc));
        }
        __syncthreads();
        float e = 0.f;
        if (tid < 144) {
            int bb = tid/36, r = tid%36, jj = r/6, ii = r%6;
            float y = (lab[bb*6+jj] == lab[bb*6+ii]) ? 1.f : 0.f;
            float d = Pm[tid] - y;
            e = d*d;
        }
        red[tid] = e;
        __syncthreads();
        for (int s = 128; s > 0; s >>= 1) {
            if (tid < s) red[tid] += red[tid+s];
            __syncthreads();
        }
        if (tid < 4) {
            float s2 = 0.f, a2 = 0.f;
            for (int jj = 0; jj < 6; jj++)
                for (int ii = 0; ii < 6; ii++) {
                    float pa = Pm[tid*36 + jj*6 + ii], pb = Pm[tid*36 + ii*6 + jj];
                    float sm = 0.5f*(pa+pb), an = 0.5f*(pa-pb);
                    s2 += sm*sm; a2 += an*an;
                }
            float sn = sqrtf(s2), anq = sqrtf(a2);
            ratio[tid] = (sn - anq)/(sn + anq);
        }
        __syncthreads();
        if (tid == 0) {
            float sl = 0.25f*(ratio[0]+ratio[1]+ratio[2]+ratio[3]);
            float euc = red[0] * (1.f/144.f);
            float cs = 0.f;
            for (int k = 0; k < 24; k++) cs += rv[k];
            out[0] = cs * (1.f/24.f);
            out[1] = euc - 0.1f*sl;
            out[2] = sl;
        }
    }
}

extern "C" void kernel_launch(void* const* d_in, const int* in_sizes, int n_in,
                              void* d_out, int out_size, void* d_ws, size_t ws_size,
                              hipStream_t stream) {
    const float* sx   = (const float*)d_in[0];
    const int*   sy   = (const int*)  d_in[1];
    const float* qx   = (const float*)d_in[2];
    const int*   qy   = (const int*)  d_in[3];
    const float* k1   = (const float*)d_in[4];
    const float* bc1  = (const float*)d_in[5];
    const float* k2   = (const float*)d_in[6];
    const float* bc2  = (const float*)d_in[7];
    const float* k3   = (const float*)d_in[8];
    const float* bc3  = (const float*)d_in[9];
    const float* Wlog = (const float*)d_in[10];
    const float* blog = (const float*)d_in[11];
    const float* Wg1  = (const float*)d_in[12];
    const float* bg1  = (const float*)d_in[13];
    const float* Wg2  = (const float*)d_in[14];
    const float* bg2  = (const float*)d_in[15];
    const float* Wf1  = (const float*)d_in[16];
    const float* bf1  = (const float*)d_in[17];
    const float* Wf2  = (const float*)d_in[18];
    const float* bf2  = (const float*)d_in[19];

    float* ws    = (float*)d_ws;
    float* feat1 = ws;                    // 786432
    float* feat2 = feat1 + 786432;        // 294912
    float* feat3 = feat2 + 294912;        // 98304
    float* mf    = feat3 + 98304;         // 1536
    float* rv    = mf    + 1536;          // 32 (24 used)
    float* xfpT  = rv    + 32;            // 64*576 = 36864
    _Float16* u16 = (_Float16*)(xfpT + 36864);  // 196608 halves
    _Float16* v16 = u16 + 196608;               // 196608 halves
    _Float16* W2h = v16 + 196608;               // 8192 halves
    float* out   = (float*)d_out;

    conv1_k <<<769,    256, 0, stream>>>(sx, qx, k1, bc1, feat1, Wg2, W2h);
    conv2_k <<<24*12,  256, 0, stream>>>(feat1, k2, bc2, feat2);
    conv3_k <<<24*8,   256, 0, stream>>>(feat2, k3, bc3, feat3, mf);
    uvcls_k <<<408,    128, 0, stream>>>(feat3, Wg1, bg1, u16, v16,
                                         mf, sy, qy, Wlog, blog, rv);
    rel_k   <<<576,    256, 0, stream>>>(u16, v16, W2h, bg2, xfpT,
                                         rv, sy, qy, Wf1, bf1, Wf2, bf2, out);
}

// Round 6
// 162.815 us; speedup vs baseline: 1.1181x; 1.1181x over previous
//
#include <hip/hip_runtime.h>

typedef _Float16 f16x8 __attribute__((ext_vector_type(8)));
typedef float f32x4 __attribute__((ext_vector_type(4)));

// Monotone rel-completion counter: exactly 576 increments per graph replay,
// so (count % 576)==575 identifies the last block of THIS replay without reset.
__device__ unsigned g_rel_done = 0;

// XCD-affinity swizzles + deep burst staging kept from rounds 3-4.
// Round 6: rel_k coherence protocol rebuilt. Round 4/5 used
// __threadfence() (buffer_wbl2) + ACQ_REL RMW (wbl2+buffer_inv) PER BLOCK
// = ~3 L2 maintenance ops x 576 blocks, 72 per XCD, serializing on each
// XCD's L2 and nuking locality (rel_k 50 us at 7-14% utilization).
// Replaced with per-location agent-scope relaxed atomics (write-through
// coherent access, no cache flush/invalidate instructions at all):
//   writers:  __hip_atomic_store(RELAXED, AGENT) + s_waitcnt vmcnt(0)
//   arrive:   RELAXED fetch_add
//   epilogue: __hip_atomic_load(RELAXED, AGENT)

// ---------------- conv1: (24,3,64,64) -> (24,32,32,32), stride2 SAME, relu
__global__ void __launch_bounds__(256) conv1_k(
        const float* __restrict__ sx, const float* __restrict__ qx,
        const float* __restrict__ w, const float* __restrict__ bias,
        float* __restrict__ out,
        const float* __restrict__ Wg2, _Float16* __restrict__ W2h) {
    if (blockIdx.x == 768) {
        for (int s = 0; s < 4; s++) {
            int slot = threadIdx.x + 256*s;      // 0..1023
            int tile = slot >> 6, lane = slot & 63;
            int kt = tile >> 2, nt = tile & 3;
            int quad = lane >> 4, col = lane & 15;
            f16x8 t;
            #pragma unroll
            for (int jj = 0; jj < 8; jj++)
                t[jj] = (_Float16)Wg2[(kt*32 + quad*8 + jj)*64 + nt*16 + col];
            *(f16x8*)&W2h[slot*8] = t;
        }
        return;
    }
    int r8 = blockIdx.x & 7, q = blockIdx.x >> 3;   // q 0..95
    int n  = (q >> 5)*8 + r8;    // 0..23
    int oc = q & 31;             // 0..31
    int bi = n / 6, si = n % 6;
    const float* inp = (si < 5) ? sx + (size_t)((bi*5+si)*3)*4096
                                : qx + (size_t)(bi*3)*4096;
    __shared__ __align__(16) float ish[3*4352];   // 3 planes, row stride 68
    __shared__ float wl[27];
    __shared__ float bl;
    const int tid = threadIdx.x;
    #pragma unroll
    for (int j = 0; j < 12; j++) {               // 3072 f32x4 burst
        int k = tid + j*256;
        f32x4 t = *(const f32x4*)&inp[k*4];
        int plane = k >> 10, rem = k & 1023, row = rem >> 4, c4 = (rem & 15)*4;
        *(f32x4*)&ish[plane*4352 + row*68 + c4] = t;
    }
    if (tid < 27) wl[tid] = w[oc*27 + tid];
    if (tid == 31) bl = bias[oc];
    __syncthreads();
    for (int idx = tid; idx < 1024; idx += 256) {
        int oy = idx >> 5, ox = idx & 31;
        float acc = bl;
        #pragma unroll
        for (int ic = 0; ic < 3; ic++) {
            const float* ip = &ish[ic*4352];
            #pragma unroll
            for (int dy = 0; dy < 3; dy++) {
                int iy = 2*oy + dy;
                if (iy >= 64) continue;
                #pragma unroll
                for (int dx = 0; dx < 3; dx++) {
                    int ix = 2*ox + dx;
                    if (ix >= 64) continue;
                    acc += ip[iy*68+ix] * wl[ic*9 + dy*3 + dx];
                }
            }
        }
        out[(size_t)(n*32+oc)*1024 + idx] = fmaxf(acc, 0.f);
    }
}

// ---------------- conv2: (24,32,32,32) -> (24,48,16,16), oc-group=4
__global__ void __launch_bounds__(256) conv2_k(
        const float* __restrict__ in, const float* __restrict__ w,
        const float* __restrict__ bias, float* __restrict__ out) {
    int r8 = blockIdx.x & 7, q = blockIdx.x >> 3;   // q 0..35
    int n   = (q / 12)*8 + r8;   // 0..23
    int ocg = q % 12;
    __shared__ __align__(16) float wl[1152];
    __shared__ __align__(16) float pin[16*1152];    // 16 planes, 32 rows x stride 36
    const int tid = threadIdx.x;
    const float* ib = in + (size_t)n*32*1024;
    // burst: half0 -> LDS
    #pragma unroll
    for (int j = 0; j < 16; j++) {
        int k = tid + j*256;                        // 0..4095
        f32x4 t = *(const f32x4*)&ib[k*4];
        int s = k >> 8, rem = k & 255, row = rem >> 3, c4 = (rem & 7)*4;
        *(f32x4*)&pin[s*1152 + row*36 + c4] = t;
    }
    // burst: half1 -> regs (stays in flight across half0's LDS writes)
    f32x4 rb[16];
    #pragma unroll
    for (int j = 0; j < 16; j++) {
        int k = tid + j*256;
        rb[j] = *(const f32x4*)&ib[16384 + k*4];
    }
    for (int e = tid; e < 288; e += 256)
        *(f32x4*)&wl[e*4] = *(const f32x4*)&w[ocg*1152 + e*4];
    __syncthreads();
    int oy = tid >> 4, ox = tid & 15;
    float a0 = bias[ocg*4+0], a1 = bias[ocg*4+1];
    float a2 = bias[ocg*4+2], a3 = bias[ocg*4+3];
    #pragma unroll 4
    for (int ic = 0; ic < 16; ic++) {
        const float* pp = &pin[ic*1152];
        float tap[9];
        #pragma unroll
        for (int dy = 0; dy < 3; dy++)
            #pragma unroll
            for (int dx = 0; dx < 3; dx++) {
                int iy = 2*oy+dy, ix = 2*ox+dx;
                tap[dy*3+dx] = (iy < 32 && ix < 32) ? pp[iy*36 + ix] : 0.f;
            }
        #pragma unroll
        for (int t = 0; t < 9; t++) {
            a0 += tap[t]*wl[0*288 + ic*9 + t];
            a1 += tap[t]*wl[1*288 + ic*9 + t];
            a2 += tap[t]*wl[2*288 + ic*9 + t];
            a3 += tap[t]*wl[3*288 + ic*9 + t];
        }
    }
    __syncthreads();
    #pragma unroll
    for (int j = 0; j < 16; j++) {
        int k = tid + j*256;
        int s = k >> 8, rem = k & 255, row = rem >> 3, c4 = (rem & 7)*4;
        *(f32x4*)&pin[s*1152 + row*36 + c4] = rb[j];
    }
    __syncthreads();
    #pragma unroll 4
    for (int ic = 16; ic < 32; ic++) {
        const float* pp = &pin[(ic-16)*1152];
        float tap[9];
        #pragma unroll
        for (int dy = 0; dy < 3; dy++)
            #pragma unroll
            for (int dx = 0; dx < 3; dx++) {
                int iy = 2*oy+dy, ix = 2*ox+dx;
                tap[dy*3+dx] = (iy < 32 && ix < 32) ? pp[iy*36 + ix] : 0.f;
            }
        #pragma unroll
        for (int t = 0; t < 9; t++) {
            a0 += tap[t]*wl[0*288 + ic*9 + t];
            a1 += tap[t]*wl[1*288 + ic*9 + t];
            a2 += tap[t]*wl[2*288 + ic*9 + t];
            a3 += tap[t]*wl[3*288 + ic*9 + t];
        }
    }
    size_t ob = (size_t)(n*48 + ocg*4)*256 + tid;
    out[ob        ] = fmaxf(a0, 0.f);
    out[ob + 256  ] = fmaxf(a1, 0.f);
    out[ob + 512  ] = fmaxf(a2, 0.f);
    out[ob + 768  ] = fmaxf(a3, 0.f);
}

// ---------------- conv3 + fused mean-pool: (24,48,16,16) -> (24,64,8,8) + mf(24,64)
__global__ void __launch_bounds__(256) conv3_k(
        const float* __restrict__ in, const float* __restrict__ w,
        const float* __restrict__ bias, float* __restrict__ out,
        float* __restrict__ mf) {
    int r8 = blockIdx.x & 7, q = blockIdx.x >> 3;   // q 0..23
    int n   = (q >> 3)*8 + r8;   // 0..23
    int ocg = q & 7;
    __shared__ __align__(16) float wl[3456];
    __shared__ __align__(16) float pin[48*320];     // 48 planes, 16 rows x stride 20
    const int tid = threadIdx.x;
    const float* ib = in + (size_t)n*48*256;
    #pragma unroll
    for (int j = 0; j < 12; j++) {                  // 3072 f32x4 burst
        int k = tid + j*256;
        f32x4 t = *(const f32x4*)&ib[k*4];
        int plane = k >> 6, rem = k & 63, row = rem >> 2, c4 = (rem & 3)*4;
        *(f32x4*)&pin[plane*320 + row*20 + c4] = t;
    }
    for (int e = tid; e < 864; e += 256)
        *(f32x4*)&wl[e*4] = *(const f32x4*)&w[ocg*3456 + e*4];
    __syncthreads();
    int pix = tid & 63, osub = tid >> 6;
    int oy = pix >> 3, ox = pix & 7;
    int ol0 = osub*2;
    float a0 = bias[ocg*8 + ol0], a1 = bias[ocg*8 + ol0 + 1];
    #pragma unroll 4
    for (int ic = 0; ic < 48; ic++) {
        const float* pp = &pin[ic*320];
        float tap[9];
        #pragma unroll
        for (int dy = 0; dy < 3; dy++)
            #pragma unroll
            for (int dx = 0; dx < 3; dx++) {
                int iy = 2*oy+dy, ix = 2*ox+dx;
                tap[dy*3+dx] = (iy < 16 && ix < 16) ? pp[iy*20 + ix] : 0.f;
            }
        #pragma unroll
        for (int t = 0; t < 9; t++) {
            a0 += tap[t]*wl[ ol0   *432 + ic*9 + t];
            a1 += tap[t]*wl[(ol0+1)*432 + ic*9 + t];
        }
    }
    float r0 = fmaxf(a0, 0.f), r1 = fmaxf(a1, 0.f);
    out[(size_t)(n*64 + ocg*8 + ol0  )*64 + pix] = r0;
    out[(size_t)(n*64 + ocg*8 + ol0+1)*64 + pix] = r1;
    #pragma unroll
    for (int off = 32; off >= 1; off >>= 1) {
        r0 += __shfl_xor(r0, off, 64);
        r1 += __shfl_xor(r1, off, 64);
    }
    if (pix == 0) {
        mf[n*64 + ocg*8 + ol0    ] = r0 * (1.f/64.f);
        mf[n*64 + ocg*8 + ol0 + 1] = r1 * (1.f/64.f);
    }
}

// ---------------- uv (blocks 0..383, f16 out, swizzled) + cls head (384..407)
__global__ void uvcls_k(const float* __restrict__ feat3, const float* __restrict__ Wg1,
                        const float* __restrict__ bg1, _Float16* __restrict__ u,
                        _Float16* __restrict__ v,
                        const float* __restrict__ mf, const int* __restrict__ sy,
                        const int* __restrict__ qy, const float* __restrict__ Wlog,
                        const float* __restrict__ blog, float* __restrict__ rv) {
    int tid = threadIdx.x;   // 128
    if (blockIdx.x >= 384) {
        int n = blockIdx.x - 384;
        if (tid >= 64) return;
        int lane = tid;
        float s = blog[lane];
        for (int c = 0; c < 64; c++) s += mf[n*64 + c] * Wlog[c*64 + lane];
        float mx = s;
        #pragma unroll
        for (int off = 32; off >= 1; off >>= 1) mx = fmaxf(mx, __shfl_xor(mx, off, 64));
        float p = __expf(s - mx);
        float se = p;
        #pragma unroll
        for (int off = 32; off >= 1; off >>= 1) se += __shfl_xor(se, off, 64);
        int bi = n/6, si = n%6;
        int lab = (si < 5) ? sy[bi*5+si] : qy[bi];
        float s_lab = __shfl(s, lab, 64);
        if (lane == 0) rv[n] = -(s_lab - mx - __logf(se));
        return;
    }
    int r8 = blockIdx.x & 7, q = blockIdx.x >> 3;  // q 0..47
    int bs = (q >> 4)*8 + r8;    // 0..23
    int pg = q & 15;             // p-group of 4
    __shared__ float a4[4][66];
    for (int e = tid; e < 264; e += 128) {
        int pl = e / 66, c = e % 66;
        int p = pg*4 + pl;
        float vv;
        if (c < 64)       vv = feat3[(size_t)(bs*64 + c)*64 + p];
        else if (c == 64) vv = (float)(p >> 3) * 0.125f;
        else              vv = (float)(p & 7) * 0.125f;
        a4[pl][c] = vv;
    }
    __syncthreads();
    float us[4] = {0.f,0.f,0.f,0.f};
    float bg = bg1[tid];
    float vs[4] = {bg,bg,bg,bg};
    for (int c = 0; c < 66; c++) {
        float wa = Wg1[c*128 + tid];
        float wb = Wg1[(66+c)*128 + tid];
        #pragma unroll
        for (int pl = 0; pl < 4; pl++) {
            us[pl] += a4[pl][c]*wa;
            vs[pl] += a4[pl][c]*wb;
        }
    }
    #pragma unroll
    for (int pl = 0; pl < 4; pl++) {
        int p = pg*4 + pl;
        u[(size_t)(bs*64+p)*128 + tid] = (_Float16)us[pl];
        v[(size_t)(bs*64+p)*128 + tid] = (_Float16)vs[pl];
    }
}

// ---------------- relation core + fused loss epilogue (last block)
// xfpT layout: [feature f (64)][gm = b*144 + (j*6+i)*4 + qc (576)]
// Coherence via per-location agent-scope relaxed atomics — NO wbl2/inv.
__global__ void __launch_bounds__(256, 2) rel_k(
        const _Float16* __restrict__ U, const _Float16* __restrict__ V,
        const _Float16* __restrict__ W2h, const float* __restrict__ bg2,
        float* __restrict__ xfpT,
        const float* __restrict__ rv,
        const int* __restrict__ sy, const int* __restrict__ qy,
        const float* __restrict__ Wf1, const float* __restrict__ bf1,
        const float* __restrict__ Wf2, const float* __restrict__ bf2,
        float* __restrict__ out) {
    __shared__ __align__(16) float smem[1792];     // union: rel {Vsh,xfred} / loss arrays
    __shared__ unsigned lastflag;
    _Float16* Vsh   = (_Float16*)smem;             // 2048 halves = 4 KB
    float*    xfred = smem + 1024;                 // [4][64]

    int r8 = blockIdx.x & 7, qq = blockIdx.x >> 3;   // batch b pinned to XCD pair
    int b = r8 >> 1;
    int m = (qq << 1) | (r8 & 1);    // 0..143
    int cb = m >> 2, qc = m & 3;
    int j = cb / 6, i = cb % 6;
    int tid  = threadIdx.x;
    int wv   = tid >> 6, lane = tid & 63;
    int col  = lane & 15, quad = lane >> 4;

    const _Float16* ub = U + (size_t)(b*6 + i)*8192;
    const _Float16* vb = V + (size_t)(b*6 + j)*8192 + qc*16*128;

    *(f16x8*)&Vsh[tid*8] = *(const f16x8*)&vb[tid*8];

    f16x8 uf[4];
    {
        const _Float16* up = ub + (wv*16 + col)*128 + quad*8;
        #pragma unroll
        for (int kt = 0; kt < 4; kt++) uf[kt] = *(const f16x8*)&up[kt*32];
    }
    f16x8 bf[4][4];
    #pragma unroll
    for (int kt = 0; kt < 4; kt++)
        #pragma unroll
        for (int nt = 0; nt < 4; nt++)
            bf[kt][nt] = *(const f16x8*)&W2h[(size_t)(((kt*4+nt)*64) + lane)*8];
    float bgv[4];
    #pragma unroll
    for (int nt = 0; nt < 4; nt++) bgv[nt] = bg2[nt*16 + col];

    __syncthreads();

    float sums[4] = {0.f,0.f,0.f,0.f};
    for (int qi = 0; qi < 16; qi++) {
        const _Float16* vp = &Vsh[qi*128 + quad*8];
        f32x4 acc[4];
        #pragma unroll
        for (int nt = 0; nt < 4; nt++)
            acc[nt] = (f32x4){bgv[nt], bgv[nt], bgv[nt], bgv[nt]};
        #pragma unroll
        for (int kt = 0; kt < 4; kt++) {
            f16x8 vf = *(const f16x8*)&vp[kt*32];
            f16x8 af = uf[kt] + vf;
            af = __builtin_elementwise_max(af, (f16x8){0,0,0,0,0,0,0,0});
            #pragma unroll
            for (int nt = 0; nt < 4; nt++)
                acc[nt] = __builtin_amdgcn_mfma_f32_16x16x32_f16(af, bf[kt][nt], acc[nt], 0, 0, 0);
        }
        #pragma unroll
        for (int nt = 0; nt < 4; nt++)
            #pragma unroll
            for (int rr = 0; rr < 4; rr++)
                sums[nt] += fmaxf(acc[nt][rr], 0.f);
    }

    #pragma unroll
    for (int nt = 0; nt < 4; nt++) {
        sums[nt] += __shfl_xor(sums[nt], 16, 64);
        sums[nt] += __shfl_xor(sums[nt], 32, 64);
    }
    if (lane < 16) {
        #pragma unroll
        for (int nt = 0; nt < 4; nt++) xfred[wv*64 + nt*16 + lane] = sums[nt];
    }
    __syncthreads();
    // coherent (agent-scope, relaxed) write-through stores — no cache flush
    if (tid < 64) {
        float val = xfred[tid] + xfred[64+tid] + xfred[128+tid] + xfred[192+tid];
        __hip_atomic_store(&xfpT[(size_t)tid*576 + (unsigned)(b*144 + m)], val,
                           __ATOMIC_RELAXED, __HIP_MEMORY_SCOPE_AGENT);
    }
    // wave 0 issued all xf stores; wait for their completion (visible at
    // the coherence point) before the arrive RMW. Per-wave vmcnt suffices.
    if (wv == 0) asm volatile("s_waitcnt vmcnt(0)" ::: "memory");
    if (tid == 0) {
        unsigned my = __hip_atomic_fetch_add(&g_rel_done, 1u, __ATOMIC_RELAXED,
                                             __HIP_MEMORY_SCOPE_AGENT);
        lastflag = ((my % 576u) == 575u) ? 1u : 0u;
    }
    __syncthreads();
    if (!lastflag) return;

    // ---- loss epilogue (same math as verified loss_k; coherent xfpT reads) ----
    {
        float* Wf1sh = smem;                 // 1024
        float* wf2sh = smem + 1024;          // 16
        float* bf1sh = smem + 1040;          // 16
        float* Pm    = smem + 1056;          // 144
        int*   lab   = (int*)(smem + 1200);  // 24
        float* red   = smem + 1232;          // 256
        float* ratio = smem + 1488;          // 4
        for (int e = tid; e < 1024; e += 256) Wf1sh[e] = Wf1[e];
        if (tid < 16) { wf2sh[tid] = Wf2[tid]; bf1sh[tid] = bf1[tid]; }
        if (tid < 24) { int bi = tid/6, si = tid%6; lab[tid] = (si < 5) ? sy[bi*5+si] : qy[bi]; }
        __syncthreads();
        if (tid < 144) {
            float hid[16];
            #pragma unroll
            for (int h = 0; h < 16; h++) hid[h] = bf1sh[h];
            for (int nn = 0; nn < 64; nn++) {
                const float* xp = &xfpT[(size_t)nn*576 + tid*4];
                float x = 0.f;
                #pragma unroll
                for (int c = 0; c < 4; c++)
                    x += __hip_atomic_load(&xp[c], __ATOMIC_RELAXED,
                                           __HIP_MEMORY_SCOPE_AGENT);
                #pragma unroll
                for (int h = 0; h < 16; h++) hid[h] += x * Wf1sh[nn*16 + h];
            }
            float sc = bf2[0];
            #pragma unroll
            for (int h = 0; h < 16; h++) sc += fmaxf(hid[h], 0.f) * wf2sh[h];
            Pm[tid] = 1.f/(1.f + __expf(-sc));
        }
        __syncthreads();
        float e = 0.f;
        if (tid < 144) {
            int bb = tid/36, r = tid%36, jj = r/6, ii = r%6;
            float y = (lab[bb*6+jj] == lab[bb*6+ii]) ? 1.f : 0.f;
            float d = Pm[tid] - y;
            e = d*d;
        }
        red[tid] = e;
        __syncthreads();
        for (int s = 128; s > 0; s >>= 1) {
            if (tid < s) red[tid] += red[tid+s];
            __syncthreads();
        }
        if (tid < 4) {
            float s2 = 0.f, a2 = 0.f;
            for (int jj = 0; jj < 6; jj++)
                for (int ii = 0; ii < 6; ii++) {
                    float pa = Pm[tid*36 + jj*6 + ii], pb = Pm[tid*36 + ii*6 + jj];
                    float sm = 0.5f*(pa+pb), an = 0.5f*(pa-pb);
                    s2 += sm*sm; a2 += an*an;
                }
            float sn = sqrtf(s2), anq = sqrtf(a2);
            ratio[tid] = (sn - anq)/(sn + anq);
        }
        __syncthreads();
        if (tid == 0) {
            float sl = 0.25f*(ratio[0]+ratio[1]+ratio[2]+ratio[3]);
            float euc = red[0] * (1.f/144.f);
            float cs = 0.f;
            for (int k = 0; k < 24; k++) cs += rv[k];
            out[0] = cs * (1.f/24.f);
            out[1] = euc - 0.1f*sl;
            out[2] = sl;
        }
    }
}

extern "C" void kernel_launch(void* const* d_in, const int* in_sizes, int n_in,
                              void* d_out, int out_size, void* d_ws, size_t ws_size,
                              hipStream_t stream) {
    const float* sx   = (const float*)d_in[0];
    const int*   sy   = (const int*)  d_in[1];
    const float* qx   = (const float*)d_in[2];
    const int*   qy   = (const int*)  d_in[3];
    const float* k1   = (const float*)d_in[4];
    const float* bc1  = (const float*)d_in[5];
    const float* k2   = (const float*)d_in[6];
    const float* bc2  = (const float*)d_in[7];
    const float* k3   = (const float*)d_in[8];
    const float* bc3  = (const float*)d_in[9];
    const float* Wlog = (const float*)d_in[10];
    const float* blog = (const float*)d_in[11];
    const float* Wg1  = (const float*)d_in[12];
    const float* bg1  = (const float*)d_in[13];
    const float* Wg2  = (const float*)d_in[14];
    const float* bg2  = (const float*)d_in[15];
    const float* Wf1  = (const float*)d_in[16];
    const float* bf1  = (const float*)d_in[17];
    const float* Wf2  = (const float*)d_in[18];
    const float* bf2  = (const float*)d_in[19];

    float* ws    = (float*)d_ws;
    float* feat1 = ws;                    // 786432
    float* feat2 = feat1 + 786432;        // 294912
    float* feat3 = feat2 + 294912;        // 98304
    float* mf    = feat3 + 98304;         // 1536
    float* rv    = mf    + 1536;          // 32 (24 used)
    float* xfpT  = rv    + 32;            // 64*576 = 36864
    _Float16* u16 = (_Float16*)(xfpT + 36864);  // 196608 halves
    _Float16* v16 = u16 + 196608;               // 196608 halves
    _Float16* W2h = v16 + 196608;               // 8192 halves
    float* out   = (float*)d_out;

    conv1_k <<<769,    256, 0, stream>>>(sx, qx, k1, bc1, feat1, Wg2, W2h);
    conv2_k <<<24*12,  256, 0, stream>>>(feat1, k2, bc2, feat2);
    conv3_k <<<24*8,   256, 0, stream>>>(feat2, k3, bc3, feat3, mf);
    uvcls_k <<<408,    128, 0, stream>>>(feat3, Wg1, bg1, u16, v16,
                                         mf, sy, qy, Wlog, blog, rv);
    rel_k   <<<576,    256, 0, stream>>>(u16, v16, W2h, bg2, xfpT,
                                         rv, sy, qy, Wf1, bf1, Wf2, bf2, out);
}